// Round 10
// baseline (234.678 us; speedup 1.0000x reference)
//
#include <hip/hip_runtime.h>

#define N_NODES 50000
#define N_EDGES 200000
#define S_DIM   8
#define F_DIM   32      // F_IN == F == 32
#define G_SEG   512
#define P_PAIRS 1024
#define A_COLS  288     // 9*32 : 8 Wk rows + 1 bk row
#define NGRP    3125    // N_NODES / 16 source-groups (buckets)
#define CAP     128     // bucket capacity: mean 64, sigma 8 -> P(overflow) ~ 1e-13
#define NBA     32      // nodes per a_gemm block
#define SCAN_B  196     // ceil(N_NODES/256)

// ---------------------------------------------------------------------------
// zero_init: cnt=0, meta=sentinel, Z1=Z2=0, pooled=0  (grid-stride)
// ---------------------------------------------------------------------------
__global__ __launch_bounds__(256)
void zero_init(unsigned int* __restrict__ meta, int* __restrict__ cnt,
               float* __restrict__ Z1, float* __restrict__ Z2,
               float* __restrict__ pooled)
{
    const int T  = gridDim.x * 256;
    const int t0 = blockIdx.x * 256 + threadIdx.x;
    for (int i = t0; i < N_NODES * F_DIM; i += T) { Z1[i] = 0.f; Z2[i] = 0.f; }
    for (int i = t0; i < NGRP * CAP;      i += T) meta[i] = 0xFFFFFFFFu;
    for (int i = t0; i < NGRP;            i += T) cnt[i] = 0;
    for (int i = t0; i < G_SEG * F_DIM;   i += T) pooled[i] = 0.f;
}

// ---------------------------------------------------------------------------
// bucket_scatter: edge -> bucket (src>>4); meta = (src<<16)|tgt; eS = evec row
// ---------------------------------------------------------------------------
__global__ __launch_bounds__(256)
void bucket_scatter(const int* __restrict__ src, const int* __restrict__ tgt,
                    const float* __restrict__ evec, int* __restrict__ cnt,
                    unsigned int* __restrict__ meta, float* __restrict__ eS)
{
    const int e = blockIdx.x * 256 + threadIdx.x;
    if (e >= N_EDGES) return;
    const unsigned sn = src[e];
    const unsigned tn = tgt[e];
    const int g = sn >> 4;
    const int pos = atomicAdd(&cnt[g], 1);
    if (pos >= CAP) return;                       // P ~ 1e-13
    meta[g * CAP + pos] = (sn << 16) | tn;
    const float4* s4 = (const float4*)(evec + (size_t)e * S_DIM);
    float4* d4 = (float4*)(eS + ((size_t)g * CAP + pos) * S_DIM);
    d4[0] = s4[0];
    d4[1] = s4[1];
}

// ---------------------------------------------------------------------------
// a_gemm: A[n][c] = sum_i h[n][i] * W[c][i]  (c<256: Wk, else bk).
// No LDS, no barrier. h rows via wave-uniform scalar loads; w in registers.
// LAYER==0: h = x row (stride 33, no relu); LAYER==1: h = h2buf (stride 32).
// ---------------------------------------------------------------------------
template <int LAYER>
__global__ __launch_bounds__(320)
void a_gemm(const float* __restrict__ hsrc,
            const float* __restrict__ Wk, const float* __restrict__ bk,
            float* __restrict__ A)
{
    const int c = threadIdx.x;
    if (c >= A_COLS) return;
    const int nb   = blockIdx.x * NBA;
    const int nmax = (N_NODES - nb < NBA) ? (N_NODES - nb) : NBA;

    float w[F_DIM];
    const int o = c & 31;
    if (c < 256) {
        const int s = c >> 5;
        #pragma unroll
        for (int i = 0; i < F_DIM; ++i) w[i] = Wk[s * (F_DIM * F_DIM) + i * F_DIM + o];
    } else {
        #pragma unroll
        for (int i = 0; i < F_DIM; ++i) w[i] = bk[i * F_DIM + o];
    }

    const int stride = (LAYER == 0) ? (F_DIM + 1) : F_DIM;
    for (int n = 0; n < nmax; ++n) {
        const float* hrow = hsrc + (size_t)(nb + n) * stride;   // uniform -> s_load
        float acc = 0.f;
        #pragma unroll
        for (int i = 0; i < F_DIM; ++i) acc += hrow[i] * w[i];
        A[(size_t)(nb + n) * A_COLS + c] = acc;
    }
}

// ---------------------------------------------------------------------------
// edge_apply: one thread per (bucket-slot, o). No LDS, no barrier, max TLP.
//   m = A[src][256+o] + sum_s eS[p][s]*A[src][s*32+o];  Z[tgt][o] += m
// Contiguous chunk per block -> bucket locality for A reads (L1/L2).
// ---------------------------------------------------------------------------
__global__ __launch_bounds__(256)
void edge_apply(const float* __restrict__ A, const unsigned int* __restrict__ meta,
                const float* __restrict__ eS, float* __restrict__ Z)
{
    const int total = NGRP * CAP * F_DIM;
    const int chunk = (total + gridDim.x - 1) / gridDim.x;
    const int lo = blockIdx.x * chunk;
    const int hi = (lo + chunk < total) ? lo + chunk : total;

    for (int idx = lo + threadIdx.x; idx < hi; idx += 256) {
        const int p = idx >> 5;
        const int o = idx & 31;
        const unsigned m = meta[p];
        if (m == 0xFFFFFFFFu) continue;           // empty slot
        const int sn = m >> 16;
        const int tn = m & 0xFFFFu;
        const float4* ev = (const float4*)(eS + (size_t)p * S_DIM);
        const float4 e0 = ev[0];
        const float4 e1 = ev[1];
        const float* Ar = A + (size_t)sn * A_COLS + o;
        float acc = Ar[8 * F_DIM];
        acc += e0.x * Ar[0 * F_DIM];
        acc += e0.y * Ar[1 * F_DIM];
        acc += e0.z * Ar[2 * F_DIM];
        acc += e0.w * Ar[3 * F_DIM];
        acc += e1.x * Ar[4 * F_DIM];
        acc += e1.y * Ar[5 * F_DIM];
        acc += e1.z * Ar[6 * F_DIM];
        acc += e1.w * Ar[7 * F_DIM];
        atomicAdd(&Z[(size_t)tn * F_DIM + o], acc);
    }
}

// ---------------------------------------------------------------------------
// combine_relu: h2buf[n][o] = relu(Z1[n][o] + b[o] + sum_i h[n][i]*root[i][o])
// (root-term applied AFTER the scatter; h = x row for layer 1)
// ---------------------------------------------------------------------------
__global__ __launch_bounds__(256)
void combine_relu(const float* __restrict__ x, const float* __restrict__ Z1,
                  const float* __restrict__ root, const float* __restrict__ bias,
                  float* __restrict__ h2buf)
{
    __shared__ float r[F_DIM * F_DIM];
    __shared__ float bsh[F_DIM];
    for (int t = threadIdx.x; t < F_DIM * F_DIM; t += 256) r[t] = root[t];
    if (threadIdx.x < F_DIM) bsh[threadIdx.x] = bias[threadIdx.x];
    __syncthreads();

    const int gid = blockIdx.x * 256 + threadIdx.x;
    if (gid >= N_NODES * F_DIM) return;
    const int n = gid >> 5, o = gid & 31;

    float acc = bsh[o] + Z1[gid];
    const float* hrow = x + (size_t)n * (F_DIM + 1);
    #pragma unroll
    for (int i = 0; i < F_DIM; ++i) acc += hrow[i] * r[i * F_DIM + o];
    h2buf[gid] = acc > 0.f ? acc : 0.f;
}

// ---------------------------------------------------------------------------
// combine_pool: v = trunc(relu(Z2[n] + b2 + h2buf[n]@root2)); run-based pool
// over sorted seg -> few atomics into pooled.
// ---------------------------------------------------------------------------
__global__ __launch_bounds__(256)
void combine_pool(const float* __restrict__ h2buf, const float* __restrict__ Z2,
                  const float* __restrict__ root, const float* __restrict__ bias,
                  const int* __restrict__ seg, float* __restrict__ pooled)
{
    __shared__ float r[F_DIM * F_DIM];
    __shared__ float bsh[F_DIM];
    for (int t = threadIdx.x; t < F_DIM * F_DIM; t += 256) r[t] = root[t];
    if (threadIdx.x < F_DIM) bsh[threadIdx.x] = bias[threadIdx.x];
    __syncthreads();

    const int o    = threadIdx.x & 31;
    const int rr   = threadIdx.x >> 5;
    const int base = blockIdx.x * 256 + rr * 32;

    int   curseg = -1;
    float acc    = 0.f;
    for (int i = 0; i < 32; ++i) {
        const int n = base + i;
        if (n >= N_NODES) break;
        const int sg = seg[n];
        if (sg != curseg) {
            if (curseg >= 0 && acc != 0.f)
                atomicAdd(&pooled[(size_t)curseg * F_DIM + o], acc);
            curseg = sg;
            acc = 0.f;
        }
        float v = Z2[(size_t)n * F_DIM + o] + bsh[o];
        const float* hrow = h2buf + (size_t)n * F_DIM;
        #pragma unroll
        for (int k = 0; k < F_DIM; ++k) v += hrow[k] * r[k * F_DIM + o];
        v = v > 0.f ? v : 0.f;
        acc += truncf(v);
    }
    if (curseg >= 0 && acc != 0.f)
        atomicAdd(&pooled[(size_t)curseg * F_DIM + o], acc);
}

// ---------------------------------------------------------------------------
// head: out[g] = relu(pooled[g].Wd + bd); result[p] = out[ib[p]] - out[ia[p]]
// ---------------------------------------------------------------------------
__global__ __launch_bounds__(512)
void head_kernel(const float* __restrict__ pooled, const float* __restrict__ Wd,
                 const float* __restrict__ bd, const int* __restrict__ ia,
                 const int* __restrict__ ib, float* __restrict__ out)
{
    __shared__ float og[G_SEG];
    const int g = threadIdx.x;
    if (g < G_SEG) {
        float acc = bd[0];
        #pragma unroll
        for (int i = 0; i < F_DIM; ++i) acc += pooled[(size_t)g * F_DIM + i] * Wd[i];
        og[g] = acc > 0.f ? acc : 0.f;
    }
    __syncthreads();
    for (int p = threadIdx.x; p < P_PAIRS; p += 512)
        out[p] = og[ib[p]] - og[ia[p]];
}

// ---------------------------------------------------------------------------
extern "C" void kernel_launch(void* const* d_in, const int* in_sizes, int n_in,
                              void* d_out, int out_size, void* d_ws, size_t ws_size,
                              hipStream_t stream)
{
    const float* x    = (const float*)d_in[0];
    const float* e    = (const float*)d_in[1];
    const int*   src  = (const int*)d_in[2];
    const int*   tgt  = (const int*)d_in[3];
    const int*   seg  = (const int*)d_in[4];
    const int*   ia   = (const int*)d_in[5];
    const int*   ib   = (const int*)d_in[6];
    const float* Wk1  = (const float*)d_in[7];
    const float* bk1  = (const float*)d_in[8];
    const float* root1= (const float*)d_in[9];
    const float* b1   = (const float*)d_in[10];
    const float* Wk2  = (const float*)d_in[11];
    const float* bk2  = (const float*)d_in[12];
    const float* root2= (const float*)d_in[13];
    const float* b2   = (const float*)d_in[14];
    const float* Wd   = (const float*)d_in[15];
    const float* bd   = (const float*)d_in[16];
    float* out = (float*)d_out;

    float* A      = (float*)d_ws;                         // 57.6 MB
    float* Z1     = A  + (size_t)N_NODES * A_COLS;        // 6.4 MB
    float* Z2     = Z1 + (size_t)N_NODES * F_DIM;         // 6.4 MB
    float* h2buf  = Z2 + (size_t)N_NODES * F_DIM;         // 6.4 MB
    float* eS     = h2buf + (size_t)N_NODES * F_DIM;      // 12.8 MB
    float* pooled = eS + (size_t)NGRP * CAP * S_DIM;      // 64 KB
    unsigned int* meta = (unsigned int*)(pooled + (size_t)G_SEG * F_DIM); // 1.6 MB
    int*   cnt    = (int*)(meta + (size_t)NGRP * CAP);    // 12.5 KB

    const int eblk = (N_EDGES + 255) / 256;
    const int ablk = (N_NODES + NBA - 1) / NBA;           // 1563
    const int cblk = (N_NODES * F_DIM + 255) / 256;       // 6250

    zero_init     <<<2048, 256, 0, stream>>>(meta, cnt, Z1, Z2, pooled);
    bucket_scatter<<<eblk, 256, 0, stream>>>(src, tgt, e, cnt, meta, eS);

    a_gemm<0>   <<<ablk, 320, 0, stream>>>(x, Wk1, bk1, A);
    edge_apply  <<<2048, 256, 0, stream>>>(A, meta, eS, Z1);
    combine_relu<<<cblk, 256, 0, stream>>>(x, Z1, root1, b1, h2buf);

    a_gemm<1>   <<<ablk, 320, 0, stream>>>(h2buf, Wk2, bk2, A);
    edge_apply  <<<2048, 256, 0, stream>>>(A, meta, eS, Z2);
    combine_pool<<<SCAN_B, 256, 0, stream>>>(h2buf, Z2, root2, b2, seg, pooled);

    head_kernel <<<1, 512, 0, stream>>>(pooled, Wd, bd, ia, ib, out);
}